// Round 9
// baseline (1130.224 us; speedup 1.0000x reference)
//
#include <hip/hip_runtime.h>
#include <hip/hip_bf16.h>

// Problem constants
#define B_    8
#define C_    64
#define P_    64
#define H_    256
#define W_    256
#define BHW_  (B_ * H_ * W_)   // 524288
#define BN_EPS 1e-5f

#define CHUNK 16
#define SWC   64               // chain LDS row stride (floats)
#define NBLK  512              // 8x8x8 tiles -> 2 blocks/CU exactly

typedef _Float16 half4v __attribute__((ext_vector_type(4)));
typedef _Float16 half8v __attribute__((ext_vector_type(8)));
typedef _Float16 half2v __attribute__((ext_vector_type(2)));
typedef __attribute__((ext_vector_type(4))) float f32x4;

// DPP lane shifts within 16-lane rows (seg dimension = low 4 lane bits).
__device__ __forceinline__ float dpp_row_shr1(float v) {   // lane n <- n-1
    return __int_as_float(__builtin_amdgcn_update_dpp(
        0, __float_as_int(v), 0x111, 0xF, 0xF, true));
}
__device__ __forceinline__ float dpp_row_shl1(float v) {   // lane n <- n+1
    return __int_as_float(__builtin_amdgcn_update_dpp(
        0, __float_as_int(v), 0x101, 0xF, 0xF, true));
}

__global__ void init_sync(unsigned* sync) {
    if (threadIdx.x < 4) sync[threadIdx.x] = 0;
}

// ---------------------------------------------------------------------------
// chain_all: ALL 64 chain steps in ONE dispatch. 4 chunks of 16 steps on a
// 64x64 LDS tile (32x32 interior, halo 16); between chunks a manual
// device-scope barrier (threadfence + atomicAdd + spin) makes the fp32 seed
// slab (channel 16k+15) visible across blocks/XCDs. No cooperative-groups
// object (R6 showed cg spills to scratch). 512 blocks x 1024 thr = 2
// blocks/CU co-resident (33.8 KB LDS, <=64 VGPR).
// ---------------------------------------------------------------------------
__global__ __launch_bounds__(1024, 8) void chain_all(
    const float* __restrict__ x,      // (B,C,H,W); only channel 0 used
    const float* __restrict__ dw_w,   // (C,3,3)
    _Float16* __restrict__ ysh,       // fp16 ys (C,B,H,W)
    float* __restrict__ seeds,        // 3 fp32 slabs (BHW each)
    unsigned* __restrict__ sync)      // 3 barrier counters (zeroed)
{
    __shared__ __align__(16) float buf0[66 * SWC];
    __shared__ __align__(16) float buf1[66 * SWC];

    const int tid = threadIdx.x;
    const int row = tid >> 4;          // 0..63
    const int seg = tid & 15;          // 0..15
    const int lx  = seg * 4;
    const int bx  = blockIdx.x;
    const int b   = bx >> 6;           // batch 0..7
    const int ty0 = ((bx >> 3) & 7) * 32;
    const int tx0 = (bx & 7) * 32;
    const int gy  = ty0 - 16 + row;
    const int gx  = tx0 - 16 + lx;
    const bool inImg = (gy >= 0) && (gy < H_) && (gx >= 0) && (gx < W_);
    const float msk = inImg ? 1.0f : 0.0f;
    const int cell = (row + 1) * SWC + lx;

    if (row == 0) {                    // zero pad rows once
        float4 z = make_float4(0.f, 0.f, 0.f, 0.f);
        *(float4*)&buf0[lx] = z;  *(float4*)&buf0[65 * SWC + lx] = z;
        *(float4*)&buf1[lx] = z;  *(float4*)&buf1[65 * SWC + lx] = z;
    }

    const bool wOK = (row >= 16) && (row < 48) && (seg >= 4) && (seg < 12);
    const size_t goff = (size_t)(b * H_ + gy) * W_ + gx;   // valid when wOK
    _Float16* gb = ysh + (wOK ? goff : 0);
    float*    sg = seeds + (wOK ? goff : 0);

    for (int k = 0; k < 4; ++k) {
        const float* in = (k == 0)
            ? x + (size_t)b * (C_ * H_ * W_)
            : seeds + (size_t)(k - 1) * BHW_ + (size_t)b * (H_ * W_);
        float4 v = make_float4(0.f, 0.f, 0.f, 0.f);
        if (inImg)
            v = *(const float4*)(in + (size_t)gy * W_ + gx);

        float* cur = buf0;
        float* nxt = buf1;
        *(float4*)&cur[cell] = v;
        __syncthreads();

        const float* dwk = dw_w + k * (CHUNK * 9);

#pragma unroll
        for (int i = 0; i < CHUNK; ++i) {
            const float w0 = dwk[i*9+0], w1 = dwk[i*9+1], w2 = dwk[i*9+2];
            const float w3 = dwk[i*9+3], w4 = dwk[i*9+4], w5 = dwk[i*9+5];
            const float w6 = dwk[i*9+6], w7 = dwk[i*9+7], w8 = dwk[i*9+8];

            float4 rT = *(const float4*)&cur[cell - SWC];
            float4 rM = *(const float4*)&cur[cell];
            float4 rB = *(const float4*)&cur[cell + SWC];

            float tl = dpp_row_shr1(rT.w), tr = dpp_row_shl1(rT.x);
            float ml = dpp_row_shr1(rM.w), mr = dpp_row_shl1(rM.x);
            float bl = dpp_row_shr1(rB.w), br = dpp_row_shl1(rB.x);

            float s0 = fmaf(tl,   w0, fmaf(rT.x, w1, fmaf(rT.y, w2,
                       fmaf(ml,   w3, fmaf(rM.x, w4, fmaf(rM.y, w5,
                       fmaf(bl,   w6, fmaf(rB.x, w7, rB.y * w8))))))));
            float s1 = fmaf(rT.x, w0, fmaf(rT.y, w1, fmaf(rT.z, w2,
                       fmaf(rM.x, w3, fmaf(rM.y, w4, fmaf(rM.z, w5,
                       fmaf(rB.x, w6, fmaf(rB.y, w7, rB.z * w8))))))));
            float s2 = fmaf(rT.y, w0, fmaf(rT.z, w1, fmaf(rT.w, w2,
                       fmaf(rM.y, w3, fmaf(rM.z, w4, fmaf(rM.w, w5,
                       fmaf(rB.y, w6, fmaf(rB.z, w7, rB.w * w8))))))));
            float s3 = fmaf(rT.z, w0, fmaf(rT.w, w1, fmaf(tr,   w2,
                       fmaf(rM.z, w3, fmaf(rM.w, w4, fmaf(mr,   w5,
                       fmaf(rB.z, w6, fmaf(rB.w, w7, br   * w8))))))));
            float4 ov;
            ov.x = fminf(fmaxf(s0, 0.f), 6.f) * msk;
            ov.y = fminf(fmaxf(s1, 0.f), 6.f) * msk;
            ov.z = fminf(fmaxf(s2, 0.f), 6.f) * msk;
            ov.w = fminf(fmaxf(s3, 0.f), 6.f) * msk;

            if (i < CHUNK - 1) {
                *(float4*)&nxt[cell] = ov;
                __syncthreads();
                float* tmp = cur; cur = nxt; nxt = tmp;
            }
            if (wOK) {
                half4v hv;
                hv.x = (_Float16)ov.x; hv.y = (_Float16)ov.y;
                hv.z = (_Float16)ov.z; hv.w = (_Float16)ov.w;
                *(half4v*)(gb + (size_t)(k * CHUNK + i) * BHW_) = hv;
                if (i == CHUNK - 1 && k < 3)
                    *(float4*)(sg + (size_t)k * BHW_) = ov;   // fp32 seed
            }
        }

        if (k < 3) {
            // ---- device-scope barrier over all 512 blocks ----
            __threadfence();                       // release seeds stores
            __syncthreads();                       // all threads' stores issued
            if (tid == 0) {
                atomicAdd(&sync[k], 1u);           // device-scope
                long long guard = 0;
                while (__hip_atomic_load(&sync[k], __ATOMIC_RELAXED,
                                         __HIP_MEMORY_SCOPE_AGENT) < NBLK) {
                    __builtin_amdgcn_s_sleep(2);
                    if (++guard > 100000000ll) break;   // hang -> clean fail
                }
            }
            __syncthreads();                       // block waits for spinner
            __threadfence();                       // acquire remote stores
        }
    }
}

// ---------------------------------------------------------------------------
// fuse_mfma (fp16 y): h = A*y via f16 MFMA, A split hi/lo fp16.
// ---------------------------------------------------------------------------
__global__ __launch_bounds__(256) void fuse_mfma(
    const _Float16* __restrict__ ysh,  // (C, BHW) fp16
    const float* __restrict__ pw_w,
    const float* __restrict__ gamma,
    const float* __restrict__ beta,
    const float* __restrict__ mean,
    const float* __restrict__ var,
    const float* __restrict__ conv_w,
    float* __restrict__ out)
{
    __shared__ _Float16 yt[64 * 88];   // [px][c], stride 88 (176 B)
    __shared__ float2 bc[P_];          // {bias, cw}

    const int tid  = threadIdx.x;
    const int lane = tid & 63;
    const int wv   = tid >> 6;         // 0..3
    const int nIdx = lane & 15;
    const int quad = lane >> 4;

    if (tid < P_) {
        float sc = gamma[tid] * rsqrtf(var[tid] + BN_EPS);
        bc[tid] = make_float2(beta[tid] - mean[tid] * sc, conv_w[tid]);
    }

    half8v Ah[4][2], Al[4][2];
#pragma unroll
    for (int pt = 0; pt < 4; ++pt) {
        const int p = pt * 16 + nIdx;
        const float sc = gamma[p] * rsqrtf(var[p] + BN_EPS);
#pragma unroll
        for (int kt = 0; kt < 2; ++kt) {
            const float* ap = pw_w + p * C_ + kt * 32 + quad * 8;
            half8v hh, ll;
#pragma unroll
            for (int j = 0; j < 8; ++j) {
                float a = ap[j] * sc;
                _Float16 h = (_Float16)a;
                hh[j] = h;
                ll[j] = (_Float16)(a - (float)h);
            }
            Ah[pt][kt] = hh;
            Al[pt][kt] = ll;
        }
    }
    __syncthreads();

    const int px2 = (tid & 31) * 2;
    const int c8  = (tid >> 5) * 8;

    for (int tile = blockIdx.x; tile < BHW_ / 64; tile += gridDim.x) {
        const size_t base = (size_t)tile * 64;

        half2v yv[8];
#pragma unroll
        for (int j = 0; j < 8; ++j)
            yv[j] = *(const half2v*)(ysh + (size_t)(c8 + j) * BHW_ + base + px2);

        __syncthreads();

        half8v e0, e1;
#pragma unroll
        for (int j = 0; j < 8; ++j) { e0[j] = yv[j].x; e1[j] = yv[j].y; }
        *(half8v*)&yt[px2 * 88 + c8]       = e0;
        *(half8v*)&yt[(px2 + 1) * 88 + c8] = e1;

        __syncthreads();

        f32x4 acc[4];
#pragma unroll
        for (int pt = 0; pt < 4; ++pt) acc[pt] = (f32x4){0.f, 0.f, 0.f, 0.f};

        const int col = wv * 16 + nIdx;
#pragma unroll
        for (int kt = 0; kt < 2; ++kt) {
            half8v Bv = *(half8v*)&yt[col * 88 + kt * 32 + quad * 8];
#pragma unroll
            for (int pt = 0; pt < 4; ++pt) {
                acc[pt] = __builtin_amdgcn_mfma_f32_16x16x32_f16(
                    Ah[pt][kt], Bv, acc[pt], 0, 0, 0);
                acc[pt] = __builtin_amdgcn_mfma_f32_16x16x32_f16(
                    Al[pt][kt], Bv, acc[pt], 0, 0, 0);
            }
        }

        float sum = 0.f;
#pragma unroll
        for (int pt = 0; pt < 4; ++pt) {
#pragma unroll
            for (int r = 0; r < 4; ++r) {
                const int p = pt * 16 + quad * 4 + r;
                float2 bcv = bc[p];
                float vv = fminf(fmaxf(acc[pt][r] + bcv.x, 0.f), 6.f);
                sum = fmaf(bcv.y, vv, sum);
            }
        }
        sum += __shfl_xor(sum, 16, 64);
        sum += __shfl_xor(sum, 32, 64);
        if (lane < 16)
            out[base + wv * 16 + lane] = sum;
    }
}

// ---------------------------------------------------------------------------
extern "C" void kernel_launch(void* const* d_in, const int* in_sizes, int n_in,
                              void* d_out, int out_size, void* d_ws, size_t ws_size,
                              hipStream_t stream) {
    const float* x      = (const float*)d_in[0];
    const float* dw_w   = (const float*)d_in[1];
    const float* pw_w   = (const float*)d_in[2];
    const float* gamma  = (const float*)d_in[3];
    const float* beta   = (const float*)d_in[4];
    const float* mean   = (const float*)d_in[5];
    const float* var    = (const float*)d_in[6];
    const float* conv_w = (const float*)d_in[7];
    float* out = (float*)d_out;

    _Float16* ysh  = (_Float16*)d_ws;                     // 64 MiB fp16 ys
    char* p        = (char*)d_ws + (size_t)C_ * BHW_ * sizeof(_Float16);
    float* seeds   = (float*)p;                           // 3 x 2 MiB fp32
    unsigned* sync = (unsigned*)(p + 3 * (size_t)BHW_ * sizeof(float));

    init_sync<<<1, 64, 0, stream>>>(sync);

    chain_all<<<NBLK, 1024, 0, stream>>>(x, dw_w, ysh, seeds, sync);

    fuse_mfma<<<1024, 256, 0, stream>>>(
        ysh, pw_w, gamma, beta, mean, var, conv_w, out);
}

// Round 10
// 267.707 us; speedup vs baseline: 4.2219x; 4.2219x over previous
//
#include <hip/hip_runtime.h>
#include <hip/hip_bf16.h>

// Problem constants
#define B_    8
#define C_    64
#define P_    64
#define H_    256
#define W_    256
#define BHW_  (B_ * H_ * W_)   // 524288
#define BN_EPS 1e-5f

#define CHUNK 16
#define SWC   64               // chain LDS row stride (floats)
#define FT_BLOCKS 2048         // fuse grid (8192 tiles / 4 per block)

typedef _Float16 half4v __attribute__((ext_vector_type(4)));
typedef _Float16 half8v __attribute__((ext_vector_type(8)));
typedef _Float16 half2v __attribute__((ext_vector_type(2)));
typedef __attribute__((ext_vector_type(4))) float f32x4;

// DPP lane shifts within 16-lane rows (seg dimension = low 4 lane bits).
__device__ __forceinline__ float dpp_row_shr1(float v) {   // lane n <- n-1
    return __int_as_float(__builtin_amdgcn_update_dpp(
        0, __float_as_int(v), 0x111, 0xF, 0xF, true));
}
__device__ __forceinline__ float dpp_row_shl1(float v) {   // lane n <- n+1
    return __int_as_float(__builtin_amdgcn_update_dpp(
        0, __float_as_int(v), 0x101, 0xF, 0xF, true));
}

// ---------------------------------------------------------------------------
// Chain kernel — R8 form VERBATIM (best measured). Wave-local spin sync,
// fp16 ys output, fp32 seed side-slab. 16 steps/launch, 4 launches.
// ---------------------------------------------------------------------------
__global__ __launch_bounds__(1024, 8) void chain_kernel(
    const float* __restrict__ src,   // seed image slab base (fp32)
    size_t src_batch_stride,         // C_*H_*W_ for x, H_*W_ for seed slab
    const float* __restrict__ dw,    // dw_w + c0*9
    _Float16* __restrict__ ysh,      // fp16 ys base (C,B,H,W)
    float* __restrict__ seed_out,    // fp32 slab for next launch's seed (or null)
    int c0)
{
    __shared__ __align__(16) float buf0[66 * SWC];
    __shared__ __align__(16) float buf1[66 * SWC];
    __shared__ int prog[16];

    const int tid  = threadIdx.x;
    const int w    = tid >> 6;         // wave 0..15
    const int lane = tid & 63;
    const int row  = tid >> 4;         // 0..63
    const int seg  = tid & 15;
    const int lx   = seg * 4;
    const int b    = blockIdx.z;
    const int ty0  = blockIdx.y * 32;
    const int tx0  = blockIdx.x * 32;
    const int gy   = ty0 - 16 + row;
    const int gx   = tx0 - 16 + lx;
    const bool inImg = (gy >= 0) && (gy < H_) && (gx >= 0) && (gx < W_);
    const float msk = inImg ? 1.0f : 0.0f;
    const int cell = (row + 1) * SWC + lx;

    if (tid < 16) prog[tid] = 0;

    float4 v = make_float4(0.f, 0.f, 0.f, 0.f);
    if (inImg)
        v = *(const float4*)(src + (size_t)b * src_batch_stride
                             + (size_t)gy * W_ + gx);
    *(float4*)&buf0[cell] = v;
    if (row == 0) {
        float4 z = make_float4(0.f, 0.f, 0.f, 0.f);
        *(float4*)&buf0[lx] = z;  *(float4*)&buf0[65 * SWC + lx] = z;
        *(float4*)&buf1[lx] = z;  *(float4*)&buf1[65 * SWC + lx] = z;
    }
    __syncthreads();                   // the ONLY block-wide barrier

    volatile int* vp = prog;
    const int wm1 = (w == 0)  ? 0  : w - 1;
    const int wp1 = (w == 15) ? 15 : w + 1;

    const bool wOK = (row >= 16) && (row < 48) && (seg >= 4) && (seg < 12);
    const size_t goff = (size_t)(b * H_ + gy) * W_ + gx;
    _Float16* gb = ysh + (size_t)c0 * BHW_ + (wOK ? goff : 0);
    float* sb = seed_out ? seed_out + (wOK ? goff : 0) : nullptr;

#pragma unroll
    for (int i = 0; i < CHUNK; ++i) {
        const float w0 = dw[i*9+0], w1 = dw[i*9+1], w2 = dw[i*9+2];
        const float w3 = dw[i*9+3], w4 = dw[i*9+4], w5 = dw[i*9+5];
        const float w6 = dw[i*9+6], w7 = dw[i*9+7], w8 = dw[i*9+8];

        while (vp[wm1] < i || vp[wp1] < i) { /* spin: broadcast ds_read */ }

        float* cur = (i & 1) ? buf1 : buf0;
        float* nxt = (i & 1) ? buf0 : buf1;

        float4 rT = *(const float4*)&cur[cell - SWC];
        float4 rM = *(const float4*)&cur[cell];
        float4 rB = *(const float4*)&cur[cell + SWC];

        float tl = dpp_row_shr1(rT.w), tr = dpp_row_shl1(rT.x);
        float ml = dpp_row_shr1(rM.w), mr = dpp_row_shl1(rM.x);
        float bl = dpp_row_shr1(rB.w), br = dpp_row_shl1(rB.x);

        float s0 = fmaf(tl,   w0, fmaf(rT.x, w1, fmaf(rT.y, w2,
                   fmaf(ml,   w3, fmaf(rM.x, w4, fmaf(rM.y, w5,
                   fmaf(bl,   w6, fmaf(rB.x, w7, rB.y * w8))))))));
        float s1 = fmaf(rT.x, w0, fmaf(rT.y, w1, fmaf(rT.z, w2,
                   fmaf(rM.x, w3, fmaf(rM.y, w4, fmaf(rM.z, w5,
                   fmaf(rB.x, w6, fmaf(rB.y, w7, rB.z * w8))))))));
        float s2 = fmaf(rT.y, w0, fmaf(rT.z, w1, fmaf(rT.w, w2,
                   fmaf(rM.y, w3, fmaf(rM.z, w4, fmaf(rM.w, w5,
                   fmaf(rB.y, w6, fmaf(rB.z, w7, rB.w * w8))))))));
        float s3 = fmaf(rT.z, w0, fmaf(rT.w, w1, fmaf(tr,   w2,
                   fmaf(rM.z, w3, fmaf(rM.w, w4, fmaf(mr,   w5,
                   fmaf(rB.z, w6, fmaf(rB.w, w7, br   * w8))))))));
        float4 ov;
        ov.x = fminf(fmaxf(s0, 0.f), 6.f) * msk;
        ov.y = fminf(fmaxf(s1, 0.f), 6.f) * msk;
        ov.z = fminf(fmaxf(s2, 0.f), 6.f) * msk;
        ov.w = fminf(fmaxf(s3, 0.f), 6.f) * msk;

        if (i < CHUNK - 1) {
            *(float4*)&nxt[cell] = ov;
            __threadfence_block();
            if (lane == 0) vp[w] = i + 1;
        }

        if (wOK) {
            half4v hv;
            hv.x = (_Float16)ov.x; hv.y = (_Float16)ov.y;
            hv.z = (_Float16)ov.z; hv.w = (_Float16)ov.w;
            *(half4v*)(gb + (size_t)i * BHW_) = hv;
            if (i == CHUNK - 1 && sb)
                *(float4*)sb = ov;
        }
    }
}

// ---------------------------------------------------------------------------
// fuse_mfma v2: double-buffered LDS, ONE barrier per tile, software
// prefetch of tile t+1's y while tile t's MFMA runs. 2048 blocks x 4 tiles.
// Correctness of single barrier: store(i)->sync(i)->read(i); a write to
// buffer parity p at iter i+2 is ordered after sync(i+1), which is after
// every wave's read(i) of that buffer.
// ---------------------------------------------------------------------------
__global__ __launch_bounds__(256) void fuse_mfma(
    const _Float16* __restrict__ ysh,  // (C, BHW) fp16
    const float* __restrict__ pw_w,
    const float* __restrict__ gamma,
    const float* __restrict__ beta,
    const float* __restrict__ mean,
    const float* __restrict__ var,
    const float* __restrict__ conv_w,
    float* __restrict__ out)
{
    __shared__ _Float16 yt[2][64 * 88];  // [buf][px][c], stride 88 (176 B)
    __shared__ float2 bc[P_];            // {bias, cw}

    const int tid  = threadIdx.x;
    const int lane = tid & 63;
    const int wv   = tid >> 6;         // 0..3
    const int nIdx = lane & 15;
    const int quad = lane >> 4;

    if (tid < P_) {
        float sc = gamma[tid] * rsqrtf(var[tid] + BN_EPS);
        bc[tid] = make_float2(beta[tid] - mean[tid] * sc, conv_w[tid]);
    }

    // A fragments: A[m=nIdx -> p (+16pt)][k=quad*8+j -> c (+32kt)], BN-folded,
    // split fp16 hi + lo.
    half8v Ah[4][2], Al[4][2];
#pragma unroll
    for (int pt = 0; pt < 4; ++pt) {
        const int p = pt * 16 + nIdx;
        const float sc = gamma[p] * rsqrtf(var[p] + BN_EPS);
#pragma unroll
        for (int kt = 0; kt < 2; ++kt) {
            const float* ap = pw_w + p * C_ + kt * 32 + quad * 8;
            half8v hh, ll;
#pragma unroll
            for (int j = 0; j < 8; ++j) {
                float a = ap[j] * sc;
                _Float16 h = (_Float16)a;
                hh[j] = h;
                ll[j] = (_Float16)(a - (float)h);
            }
            Ah[pt][kt] = hh;
            Al[pt][kt] = ll;
        }
    }

    const int px2 = (tid & 31) * 2;          // 2 consecutive px per thread
    const int c8  = (tid >> 5) * 8;          // 8 channels per thread
    const int col = wv * 16 + nIdx;

    const int nTiles = BHW_ / 64;            // 8192
    int tile = blockIdx.x;

    // prologue: load tile 0's y
    half2v yv[8];
#pragma unroll
    for (int j = 0; j < 8; ++j)
        yv[j] = *(const half2v*)(ysh + (size_t)(c8 + j) * BHW_
                                 + (size_t)tile * 64 + px2);

    __syncthreads();                   // bc visible (also first LDS free)

    for (int iter = 0; tile < nTiles; ++iter) {
        _Float16* buf = yt[iter & 1];

        // repack + stage into LDS
        half8v e0, e1;
#pragma unroll
        for (int j = 0; j < 8; ++j) { e0[j] = yv[j].x; e1[j] = yv[j].y; }
        *(half8v*)&buf[px2 * 88 + c8]       = e0;
        *(half8v*)&buf[(px2 + 1) * 88 + c8] = e1;

        // prefetch next tile's y (retires under this tile's MFMA)
        const int next = tile + FT_BLOCKS;
        if (next < nTiles) {
#pragma unroll
            for (int j = 0; j < 8; ++j)
                yv[j] = *(const half2v*)(ysh + (size_t)(c8 + j) * BHW_
                                         + (size_t)next * 64 + px2);
        }

        __syncthreads();               // staged data visible

        f32x4 acc[4];
#pragma unroll
        for (int pt = 0; pt < 4; ++pt) acc[pt] = (f32x4){0.f, 0.f, 0.f, 0.f};

#pragma unroll
        for (int kt = 0; kt < 2; ++kt) {
            half8v Bv = *(half8v*)&buf[col * 88 + kt * 32 + quad * 8];
#pragma unroll
            for (int pt = 0; pt < 4; ++pt) {
                acc[pt] = __builtin_amdgcn_mfma_f32_16x16x32_f16(
                    Ah[pt][kt], Bv, acc[pt], 0, 0, 0);
                acc[pt] = __builtin_amdgcn_mfma_f32_16x16x32_f16(
                    Al[pt][kt], Bv, acc[pt], 0, 0, 0);
            }
        }

        // epilogue: D[m=quad*4+r (+16pt) -> p][n=nIdx -> px]
        float sum = 0.f;
#pragma unroll
        for (int pt = 0; pt < 4; ++pt) {
#pragma unroll
            for (int r = 0; r < 4; ++r) {
                const int p = pt * 16 + quad * 4 + r;
                float2 bcv = bc[p];
                float vv = fminf(fmaxf(acc[pt][r] + bcv.x, 0.f), 6.f);
                sum = fmaf(bcv.y, vv, sum);
            }
        }
        sum += __shfl_xor(sum, 16, 64);
        sum += __shfl_xor(sum, 32, 64);
        if (lane < 16)
            out[(size_t)tile * 64 + wv * 16 + lane] = sum;

        tile = next;
    }
}

// ---------------------------------------------------------------------------
extern "C" void kernel_launch(void* const* d_in, const int* in_sizes, int n_in,
                              void* d_out, int out_size, void* d_ws, size_t ws_size,
                              hipStream_t stream) {
    const float* x      = (const float*)d_in[0];
    const float* dw_w   = (const float*)d_in[1];
    const float* pw_w   = (const float*)d_in[2];
    const float* gamma  = (const float*)d_in[3];
    const float* beta   = (const float*)d_in[4];
    const float* mean   = (const float*)d_in[5];
    const float* var    = (const float*)d_in[6];
    const float* conv_w = (const float*)d_in[7];
    float* out = (float*)d_out;

    _Float16* ysh = (_Float16*)d_ws;                       // 64 MiB fp16 ys
    float* seeds = (float*)((char*)d_ws + (size_t)C_ * BHW_ * sizeof(_Float16));

    dim3 cgrid(W_ / 32, H_ / 32, B_);                      // 512 blocks

    chain_kernel<<<cgrid, 1024, 0, stream>>>(
        x, (size_t)C_ * H_ * W_, dw_w, ysh, seeds, 0);
    for (int k = 1; k < C_ / CHUNK; ++k) {
        float* seed_out = (k < 3) ? seeds + (size_t)k * BHW_ : nullptr;
        chain_kernel<<<cgrid, 1024, 0, stream>>>(
            seeds + (size_t)(k - 1) * BHW_, (size_t)H_ * W_,
            dw_w + k * CHUNK * 9, ysh, seed_out, k * CHUNK);
    }

    fuse_mfma<<<FT_BLOCKS, 256, 0, stream>>>(
        ysh, pw_w, gamma, beta, mean, var, conv_w, out);
}